// Round 7
// baseline (2606.811 us; speedup 1.0000x reference)
//
#include <hip/hip_runtime.h>
#include <hip/hip_cooperative_groups.h>
#include <hip/hip_fp8.h>
#include <hip/hip_fp16.h>

namespace cg = cooperative_groups;

#define BS 256
#define MAXIT 8

// ctrl int-index layout (ctrl is 256B-aligned, 4096B)
#define C_DONE  0
#define C_CNT   1
#define C_HSTAR 3
#define C_R     4
#define C_FS    8   // frontier-size slots [it], 8..18
#define C_NEWA  20  // newly-claimed slots [it], 20..29
#define C_LOSS  32  // float
#define C_SUM1  64  // float[64]
#define C_SUM2  128 // float[64]
#define C_V1    192 // float[64]
#define C_V2    256 // float[64]

typedef __hip_fp8_e4m3 fp8;

// agent-scope atomics: bypass per-CU L1 (cross-block visibility inside one kernel)
#define ALr(p)   __hip_atomic_load((p), __ATOMIC_RELAXED, __HIP_MEMORY_SCOPE_AGENT)
#define ALa(p)   __hip_atomic_load((p), __ATOMIC_ACQUIRE, __HIP_MEMORY_SCOPE_AGENT)
#define ASr(p,v) __hip_atomic_store((p),(v), __ATOMIC_RELAXED, __HIP_MEMORY_SCOPE_AGENT)
#define ASl(p,v) __hip_atomic_store((p),(v), __ATOMIC_RELEASE, __HIP_MEMORY_SCOPE_AGENT)

__device__ inline float softplusf(float x){
  return fmaxf(x, 0.f) + log1pf(expf(-fabsf(x)));
}

// ---------------- CSR build ----------------
__global__ void k_deg2(const int* __restrict__ src, const int* __restrict__ dst, int E,
                       int* __restrict__ cntS, int* __restrict__ cntD){
  int i=blockIdx.x*BS+threadIdx.x, st=gridDim.x*BS;
  for(; i<E; i+=st){ atomicAdd(&cntS[src[i]],1); atomicAdd(&cntD[dst[i]],1); }
}

__global__ void k_blocksum(const int* __restrict__ a, int n, int* __restrict__ part){
  __shared__ int s[BS];
  int t=threadIdx.x, i=blockIdx.x*BS+t;
  s[t] = (i<n)? a[i] : 0;
  __syncthreads();
  for(int o=BS/2;o>0;o>>=1){ if(t<o) s[t]+=s[t+o]; __syncthreads(); }
  if(t==0) part[blockIdx.x]=s[0];
}

// single-block parallel exclusive scan (in place), total at a[n]
__global__ void k_scan_block(int* a, int n){
  __shared__ int s[BS];
  __shared__ int carry;
  int t=threadIdx.x;
  if(t==0) carry=0;
  __syncthreads();
  for(int base=0; base<n; base+=BS){
    int i=base+t;
    int v=(i<n)? a[i] : 0;
    s[t]=v; __syncthreads();
    for(int o=1;o<BS;o<<=1){
      int x=(t>=o)? s[t-o]:0;
      __syncthreads();
      if(t>=o) s[t]+=x;
      __syncthreads();
    }
    if(i<n) a[i]=carry+s[t]-v;
    __syncthreads();
    if(t==0) carry+=s[BS-1];
    __syncthreads();
  }
  if(t==0) a[n]=carry;
}

__global__ void k_rowptr(const int* __restrict__ cnt, const int* __restrict__ part, int n, int nb,
                         int* __restrict__ rowptr, int* __restrict__ cursor){
  __shared__ int s[BS];
  int b=blockIdx.x, t=threadIdx.x, i=b*BS+t;
  int v=(i<n)?cnt[i]:0;
  s[t]=v; __syncthreads();
  for(int o=1;o<BS;o<<=1){
    int x=(t>=o)? s[t-o]:0;
    __syncthreads();
    if(t>=o) s[t]+=x;
    __syncthreads();
  }
  int excl = s[t]-v+part[b];
  if(i<n){ rowptr[i]=excl; cursor[i]=excl; }
  if(b==0&&t==0) rowptr[n]=part[nb];
}

__global__ void k_scatter2(const int* __restrict__ src, const int* __restrict__ dst, int E,
                           int* __restrict__ curD, int* __restrict__ colD,
                           int* __restrict__ curS, int* __restrict__ colS){
  int i=blockIdx.x*BS+threadIdx.x, st=gridDim.x*BS;
  for(; i<E; i+=st){
    int s=src[i], d=dst[i];
    colD[atomicAdd(&curD[d],1)] = s;   // in-edges:  col = src
    colS[atomicAdd(&curS[s],1)] = d;   // out-edges: col = dst
  }
}

// ---------------- FW = feat @ W_enc  (fp8 e4m3 output) ----------------
__global__ void k_fw(const float* __restrict__ feat, const float* __restrict__ W,
                     fp8* __restrict__ FW, int N){
  __shared__ float sW[64*64];
  __shared__ float sf[4][64];
  int t=threadIdx.x;
  for(int i=t;i<64*64;i+=BS) sW[i]=W[i];
  __syncthreads();
  int j=t&63, r=t>>6;
  int ngroups=(N+3)>>2;
  for(int g=blockIdx.x; g<ngroups; g+=gridDim.x){
    int vr=g*4+r;
    sf[r][j] = (vr<N)? feat[vr*64+j] : 0.f;
    __syncthreads();
    if(vr<N){
      float acc=0.f;
      #pragma unroll
      for(int d=0;d<64;d++) acc += sf[r][d]*sW[d*64+j];
      FW[vr*64+j]=fp8(acc);
    }
    __syncthreads();
  }
}

// FWn[v] = FW[perm_neg[v]]  (row permute, 16 dwords per 64B row)
__global__ void k_permrows(const unsigned* __restrict__ FW, const int* __restrict__ pn,
                           unsigned* __restrict__ FWn, int N){
  int i=blockIdx.x*BS+threadIdx.x, st=gridDim.x*BS;
  int tot=N*16;
  for(; i<tot; i+=st){
    int v=i>>4, e=i&15;
    FWn[i]=FW[pn[v]*16+e];
  }
}

// ---------------- cooperative per-perm pipeline: BFS + keep-mask ----------------
__global__ void __launch_bounds__(BS) k_permpipe(
    const int* __restrict__ rowptrS, const int* __restrict__ colS,
    int* __restrict__ hop, const int* __restrict__ perm,
    int* __restrict__ ctrl, int* __restrict__ hist,
    unsigned* __restrict__ bits, int* __restrict__ wordpref,
    int* __restrict__ fr0, int* __restrict__ fr1,
    int* __restrict__ keepPk, int N, int target, int pi, int nw)
{
  cg::grid_group grid = cg::this_grid();
  int t=threadIdx.x;
  int gtid=blockIdx.x*BS+t, gst=gridDim.x*BS;
  int root=perm[0];

  // ---- phase 0: init ----
  for(int v=gtid; v<N; v+=gst) hop[v]=(v==root)?0:N;
  for(int i=gtid; i<nw; i+=gst) bits[i]=0u;
  if(gtid<64) hist[gtid]=0;
  if(gtid==0){
    ctrl[C_CNT]=1;
    ASr(&ctrl[C_DONE],0);
    for(int k=0;k<=MAXIT;k++) ASr(&ctrl[C_FS+k], (k==0)?1:0);
    for(int k=0;k<MAXIT;k++)  ASr(&ctrl[C_NEWA+k],0);
    ASr(&fr0[0], root);
    if(pi==0) ((float*)ctrl)[C_LOSS]=0.f;
  }
  __threadfence();
  grid.sync();

  // ---- BFS level loop (early exit when cnt>target) ----
  for(int it=0; it<MAXIT; ++it){
    int fs = ALa(&ctrl[C_FS+it]);
    int lvl = it+1;
    int* frCur = (it&1)? fr1 : fr0;
    int* frNext= (it&1)? fr0 : fr1;
    for(int f=gtid; f<fs; f+=gst){
      int s=ALr(&frCur[f]);
      int b=rowptrS[s], e=rowptrS[s+1];
      for(int j=b;j<e;j++){
        int d=colS[j];
        if(d==s) continue;                  // weight-0 self-loop
        if(hop[d]==N){                      // stale-tolerant pre-check; CAS is authoritative
          if(atomicCAS(&hop[d],N,lvl)==N){
            int p=atomicAdd(&ctrl[C_NEWA+it],1);
            ASr(&frNext[p],d);
          }
        }
      }
    }
    __threadfence();
    grid.sync();
    if(blockIdx.x==0){
      int newly = ALr(&ctrl[C_NEWA+it]);
      if(newly != 0){
        if(t==0){
          int c = ctrl[C_CNT] + newly;     // C_CNT touched only by block 0
          ctrl[C_CNT]=c;
          ASr(&ctrl[C_FS+it+1], newly);
          if(c>target) ASl(&ctrl[C_DONE],1);
        }
      } else {
        // stuck: seed unreached node with min (perm,v) key — rare path
        __shared__ unsigned long long sk[BS];
        unsigned long long key=~0ull;
        for(int v=t; v<N; v+=BS)
          if(ALr(&hop[v])==N){
            unsigned long long k=((unsigned long long)(unsigned)perm[v]<<32)|(unsigned)v;
            if(k<key)key=k;
          }
        sk[t]=key; __syncthreads();
        for(int o=BS/2;o>0;o>>=1){ if(t<o&&sk[t+o]<sk[t])sk[t]=sk[t+o]; __syncthreads(); }
        if(t==0){
          int c=ctrl[C_CNT], fsz=0;
          if(sk[0]!=~0ull){
            int idx=(int)(sk[0]&0xffffffffu);
            ASr(&hop[idx],lvl);
            ASr(&frNext[0],idx);
            fsz=1; c+=1;
          }
          ctrl[C_CNT]=c;
          ASr(&ctrl[C_FS+it+1],fsz);
          if(c>target) ASl(&ctrl[C_DONE],1);
        }
      }
      __threadfence();
    }
    grid.sync();
    if(ALa(&ctrl[C_DONE])) break;          // uniform across grid (read after sync)
  }

  // ---- hop histogram ----
  __shared__ int lh[64];
  if(t<64) lh[t]=0;
  __syncthreads();
  for(int v=gtid; v<N; v+=gst) atomicAdd(&lh[min(ALr(&hop[v]),63)],1);
  __syncthreads();
  if(t<64) atomicAdd(&hist[t], lh[t]);
  __threadfence();
  grid.sync();

  // ---- cutoff ----
  if(blockIdx.x==0 && t==0){
    int c=0,hstar=63,r=0;
    for(int h=0;h<64;h++){
      int x=ALr(&hist[h]);
      if(c+x>target){ hstar=h; r=target-c; break; }
      c+=x;
    }
    ASr(&ctrl[C_HSTAR],hstar);
    ASl(&ctrl[C_R],r);
    __threadfence();
  }
  grid.sync();
  int hstar=ALa(&ctrl[C_HSTAR]), rr=ALr(&ctrl[C_R]);

  // ---- flag bits (perm positions of hstar-level nodes) ----
  for(int v=gtid; v<N; v+=gst){
    if(min(ALr(&hop[v]),63)==hstar){
      int p=perm[v];
      atomicOr(&bits[p>>5], 1u<<(p&31));
    }
  }
  __threadfence();
  grid.sync();

  // ---- word-popcount exclusive scan (block 0) ----
  if(blockIdx.x==0){
    __shared__ int ss[BS];
    __shared__ int carry;
    if(t==0) carry=0;
    __syncthreads();
    for(int base=0; base<nw; base+=BS){
      int i=base+t;
      int v=(i<nw)? __popc(ALr(&bits[i])) : 0;
      ss[t]=v; __syncthreads();
      for(int o=1;o<BS;o<<=1){
        int x=(t>=o)? ss[t-o]:0;
        __syncthreads();
        if(t>=o) ss[t]+=x;
        __syncthreads();
      }
      if(i<nw) wordpref[i]=carry+ss[t]-v;  // write-through; readers first-touch after sync
      __syncthreads();
      if(t==0) carry+=ss[BS-1];
      __syncthreads();
    }
    __threadfence();
  }
  grid.sync();

  // ---- keep mask (packed 2-bit) ----
  for(int v=gtid; v<N; v+=gst){
    int h=min(ALr(&hop[v]),63), kp=0;
    if(h<hstar) kp=1;
    else if(h==hstar){
      int p=perm[v];
      unsigned mask=(2u<<(p&31))-1u;
      int cum=wordpref[p>>5]+__popc(ALr(&bits[p>>5])&mask);
      kp=(cum<=rr);
    }
    if(pi==0) keepPk[v]=kp; else keepPk[v]|=kp<<1;
  }
}

// ---------------- fused mega gather: pos/neg rows + both subgraph summaries ----------------
// lane L = (edge L>>2, 16-dim slice L&3); one dwordx4 gather covers 16 edges.
__global__ void __launch_bounds__(BS, 8) k_mega(
    const int* __restrict__ rowptr, const int* __restrict__ col,
    const unsigned char* __restrict__ FW8, const unsigned char* __restrict__ FWn8,
    const int* __restrict__ keepPk,
    __half* __restrict__ P, __half* __restrict__ Q,
    float* __restrict__ sp1, float* __restrict__ sp2, int N){
  __shared__ uint4 ldsA4[4][16][4];
  __shared__ uint4 ldsB4[4][16][4];
  __shared__ float sh1[4][64], sh2[4][64];
  int t=threadIdx.x, lane=t&63, w=t>>6;
  int eidx=lane>>2, q=lane&3;
  volatile unsigned char* lA=(volatile unsigned char*)&ldsA4[w][0][0];
  volatile unsigned char* lB=(volatile unsigned char*)&ldsB4[w][0][0];
  int wid=(blockIdx.x*BS+t)>>6, nw=(gridDim.x*BS)>>6;
  float acc1=0.f, acc2=0.f;
  for(int v=wid; v<N; v+=nw){
    int b=rowptr[v], e=rowptr[v+1];
    int deg=e-b;
    int kv=keepPk[v];
    float ap=0.f, an=0.f, a1=0.f, a2=0.f;
    int c1t=0, c2t=0;
    for(int c0=b; c0<e; c0+=16){
      int n=min(16, e-c0);
      uint4 wa=make_uint4(0,0,0,0), wb=make_uint4(0,0,0,0);
      int kk=0;
      if(eidx<n){
        int s=col[c0+eidx];
        kk=keepPk[s];
        size_t off=((size_t)s<<6)+(q<<4);
        wa=*reinterpret_cast<const uint4*>(FW8+off);
        wb=*reinterpret_cast<const uint4*>(FWn8+off);
      }
      volatile unsigned* pa=(volatile unsigned*)&ldsA4[w][eidx][q];
      volatile unsigned* pb=(volatile unsigned*)&ldsB4[w][eidx][q];
      pa[0]=wa.x; pa[1]=wa.y; pa[2]=wa.z; pa[3]=wa.w;
      pb[0]=wb.x; pb[1]=wb.y; pb[2]=wb.z; pb[3]=wb.w;
      unsigned long long bal1=__ballot(q==0 && (kk&1));
      unsigned long long bal2=__ballot(q==0 && (kk&2));
      c1t+=__popcll(bal1); c2t+=__popcll(bal2);
      if(n==16){
        #pragma unroll
        for(int ee=0; ee<16; ee++){
          fp8 ha, hb;
          ha.__x=lA[ee*64+lane];
          hb.__x=lB[ee*64+lane];
          float fa=(float)ha, fb=(float)hb;
          ap+=fa; an+=fb;
          a1 += ((bal1>>(ee*4))&1) ? fa : 0.f;
          a2 += ((bal2>>(ee*4))&1) ? fa : 0.f;
        }
      } else {
        for(int ee=0; ee<n; ee++){
          fp8 ha, hb;
          ha.__x=lA[ee*64+lane];
          hb.__x=lB[ee*64+lane];
          float fa=(float)ha, fb=(float)hb;
          ap+=fa; an+=fb;
          a1 += ((bal1>>(ee*4))&1) ? fa : 0.f;
          a2 += ((bal2>>(ee*4))&1) ? fa : 0.f;
        }
      }
    }
    float invd=1.f/(float)deg;              // deg >= 1 (self-loops)
    float p =fmaxf(ap*invd, 0.f);
    float qq=fmaxf(an*invd, 0.f);
    P[(size_t)v*64+lane]=__float2half(p);
    Q[(size_t)v*64+lane]=__float2half(qq);
    if(kv&1) acc1+=fmaxf(a1/(float)max(c1t,1), 0.f);
    if(kv&2) acc2+=fmaxf(a2/(float)max(c2t,1), 0.f);
  }
  sh1[w][lane]=acc1; sh2[w][lane]=acc2;
  __syncthreads();
  if(w==0){
    sp1[blockIdx.x*64+lane]=sh1[0][lane]+sh1[1][lane]+sh1[2][lane]+sh1[3][lane];
    sp2[blockIdx.x*64+lane]=sh2[0][lane]+sh2[1][lane]+sh2[2][lane]+sh2[3][lane];
  }
}

// stage 1: 128 blocks, block b reduces rows [b*rows, (b+1)*rows) of sp1/sp2
__global__ void k_reduce_s1(const float* __restrict__ sp1, const float* __restrict__ sp2,
                            int nb, int rows, float* __restrict__ sp1b, float* __restrict__ sp2b){
  __shared__ float s[BS];
  int t=threadIdx.x, lane=t&63, p=t>>6;
  int base=blockIdx.x*rows;
  float a=0.f;
  for(int r=p; r<rows; r+=4){
    int row=base+r;
    if(row<nb) a+=sp1[row*64+lane];
  }
  s[t]=a; __syncthreads();
  if(t<64) sp1b[blockIdx.x*64+t]=s[t]+s[t+64]+s[t+128]+s[t+192];
  __syncthreads();
  a=0.f;
  for(int r=p; r<rows; r+=4){
    int row=base+r;
    if(row<nb) a+=sp2[row*64+lane];
  }
  s[t]=a; __syncthreads();
  if(t<64) sp2b[blockIdx.x*64+t]=s[t]+s[t+64]+s[t+128]+s[t+192];
}

// stage 2: single block over nb2 (=128) rows
__global__ void k_reduce_s2(const float* __restrict__ sp1b, const float* __restrict__ sp2b,
                            int nb2, float* __restrict__ cf){
  __shared__ float s[BS];
  int t=threadIdx.x, lane=t&63, p=t>>6;
  float a=0.f;
  for(int b=p;b<nb2;b+=4) a+=sp1b[b*64+lane];
  s[t]=a; __syncthreads();
  if(t<64) cf[C_SUM1+t]=s[t]+s[t+64]+s[t+128]+s[t+192];
  __syncthreads();
  a=0.f;
  for(int b=p;b<nb2;b+=4) a+=sp2b[b*64+lane];
  s[t]=a; __syncthreads();
  if(t<64) cf[C_SUM2+t]=s[t]+s[t+64]+s[t+128]+s[t+192];
}

__global__ void k_sumv(const float* __restrict__ Wd, float* __restrict__ cf,
                       int sumoff, int voff, float invk){
  __shared__ float s[64];
  int t=threadIdx.x;
  if(t<64){
    float x=cf[sumoff+t]*invk;
    s[t]=1.f/(1.f+expf(-x));
  }
  __syncthreads();
  if(t<64){
    float a=0.f;
    #pragma unroll
    for(int d=0;d<64;d++) a+=Wd[t*64+d]*s[d];
    cf[voff+t]=a;
  }
}

// ---------------- streaming BCE loss over materialized P/Q (thread per node) ----------------
__global__ void k_loss2(const __half* __restrict__ P, const __half* __restrict__ Q,
                        float* __restrict__ cf, int N){
  __shared__ float sv1[64], sv2[64];
  __shared__ float sred[BS];
  int t=threadIdx.x;
  if(t<64){ sv1[t]=cf[C_V1+t]; sv2[t]=cf[C_V2+t]; }
  __syncthreads();
  int i=blockIdx.x*BS+t, st=gridDim.x*BS;
  float acc=0.f;
  for(int v=i; v<N; v+=st){
    const uint4* pr=(const uint4*)(P+(size_t)v*64);
    const uint4* qr=(const uint4*)(Q+(size_t)v*64);
    float a1=0.f,a2=0.f,b1=0.f,b2=0.f;
    #pragma unroll
    for(int c=0;c<8;c++){
      uint4 pu=pr[c], qu=qr[c];
      unsigned arr[4]={pu.x,pu.y,pu.z,pu.w};
      unsigned brr[4]={qu.x,qu.y,qu.z,qu.w};
      #pragma unroll
      for(int j=0;j<4;j++){
        int d=c*8+j*2;
        __half2 ph=*(const __half2*)&arr[j];
        __half2 qh=*(const __half2*)&brr[j];
        float2 pf=__half22float2(ph);
        float2 qf=__half22float2(qh);
        a1=fmaf(pf.x,sv1[d],a1); a1=fmaf(pf.y,sv1[d+1],a1);
        a2=fmaf(pf.x,sv2[d],a2); a2=fmaf(pf.y,sv2[d+1],a2);
        b1=fmaf(qf.x,sv1[d],b1); b1=fmaf(qf.y,sv1[d+1],b1);
        b2=fmaf(qf.x,sv2[d],b2); b2=fmaf(qf.y,sv2[d+1],b2);
      }
    }
    acc += softplusf(-a1)+softplusf(b1)+softplusf(-a2)+softplusf(b2);
  }
  sred[t]=acc;
  __syncthreads();
  for(int o=BS/2;o>0;o>>=1){ if(t<o) sred[t]+=sred[t+o]; __syncthreads(); }
  if(t==0) atomicAdd(&cf[C_LOSS], sred[0]);
}

__global__ void k_final(const float* __restrict__ cf, float* __restrict__ out, int N){
  if(blockIdx.x||threadIdx.x) return;
  out[0]=cf[C_LOSS]/(float)N;
}

extern "C" void kernel_launch(void* const* d_in, const int* in_sizes, int n_in,
                              void* d_out, int out_size, void* d_ws, size_t ws_size,
                              hipStream_t stream) {
  const float* feat    = (const float*)d_in[0];
  const float* Wenc    = (const float*)d_in[1];
  const float* Wdisc   = (const float*)d_in[2];
  const int*   src     = (const int*)d_in[3];
  const int*   dst     = (const int*)d_in[4];
  const int*   permneg = (const int*)d_in[5];
  const int*   perm1   = (const int*)d_in[6];
  const int*   perm2   = (const int*)d_in[7];
  float* out = (float*)d_out;

  int N = in_sizes[5];
  int E = in_sizes[3];
  int target = (int)((double)N*0.8);
  int NB = (N+BS-1)/BS;
  int WORDS = (N+31)/32;
  int gE = (E+BS-1)/BS; if(gE>4096) gE=4096;
  const int SUBB = 2048;
  const int R1B = 128, R1ROWS = SUBB/R1B;
  const int COOPB = 256;

  // workspace carve (256B-aligned chunks)
  char* w = (char*)d_ws;
  auto alloc = [&](size_t bytes)->void*{
    void* p = (void*)w;
    w += (bytes + 255) & ~(size_t)255;
    return p;
  };
  size_t szN = ((size_t)N*4 + 255) & ~(size_t)255;
  int*      ctrl    = (int*)     alloc(4096);
  int*      cntD    = (int*)     alloc(szN);     // cntD+cntS contiguous -> one memset
  int*      cntS    = (int*)     alloc(szN);
  int*      rowptrD = (int*)     alloc((size_t)(N+1)*4);
  int*      rowptrS = (int*)     alloc((size_t)(N+1)*4);
  int*      curD    = (int*)     alloc((size_t)N*4);
  int*      curS    = (int*)     alloc((size_t)N*4);
  int*      colD    = (int*)     alloc((size_t)E*4);
  int*      colS    = (int*)     alloc((size_t)E*4);
  int*      hop     = (int*)     alloc((size_t)N*4);
  int*      keepPk  = (int*)     alloc((size_t)N*4);
  unsigned* bits    = (unsigned*)alloc((size_t)WORDS*4);
  int*      wordpref= (int*)     alloc((size_t)(WORDS+1)*4);
  int*      fr0     = (int*)     alloc((size_t)N*4);
  int*      fr1     = (int*)     alloc((size_t)N*4);
  int*      part    = (int*)     alloc((size_t)(NB+2)*4);
  int*      hist    = (int*)     alloc(64*4);
  fp8*      FW      = (fp8*)     alloc((size_t)N*64);
  fp8*      FWn     = (fp8*)     alloc((size_t)N*64);
  __half*   P       = (__half*)  alloc((size_t)N*64*2);
  __half*   Q       = (__half*)  alloc((size_t)N*64*2);
  float*    sp1     = (float*)   alloc((size_t)SUBB*64*4);
  float*    sp2     = (float*)   alloc((size_t)SUBB*64*4);
  float*    sp1b    = (float*)   alloc((size_t)R1B*64*4);
  float*    sp2b    = (float*)   alloc((size_t)R1B*64*4);
  float*    cf = (float*)ctrl;

  // --- build both CSRs ---
  hipMemsetAsync(cntD, 0, 2*szN, stream);
  k_deg2      <<<gE, BS, 0, stream>>>(src, dst, E, cntS, cntD);
  k_blocksum  <<<NB, BS, 0, stream>>>(cntD, N, part);
  k_scan_block<<<1,  BS, 0, stream>>>(part, NB);
  k_rowptr    <<<NB, BS, 0, stream>>>(cntD, part, N, NB, rowptrD, curD);
  k_blocksum  <<<NB, BS, 0, stream>>>(cntS, N, part);
  k_scan_block<<<1,  BS, 0, stream>>>(part, NB);
  k_rowptr    <<<NB, BS, 0, stream>>>(cntS, part, N, NB, rowptrS, curS);
  k_scatter2  <<<gE, BS, 0, stream>>>(src, dst, E, curD, colD, curS, colS);

  // --- FW = feat @ W_enc (fp8), FWn = FW[perm_neg] ---
  k_fw      <<<2048, BS, 0, stream>>>(feat, Wenc, FW, N);
  k_permrows<<<4096, BS, 0, stream>>>((const unsigned*)FW, permneg, (unsigned*)FWn, N);

  // --- per-perm cooperative pipeline (BFS + keep mask), one launch each ---
  const int* perms[2] = {perm1, perm2};
  for(int pi=0; pi<2; pi++){
    const int* permArg = perms[pi];
    int piArg = pi;
    void* args[] = { (void*)&rowptrS, (void*)&colS, (void*)&hop, (void*)&permArg,
                     (void*)&ctrl, (void*)&hist, (void*)&bits, (void*)&wordpref,
                     (void*)&fr0, (void*)&fr1, (void*)&keepPk,
                     (void*)&N, (void*)&target, (void*)&piArg, (void*)&WORDS };
    hipLaunchCooperativeKernel((void*)k_permpipe, dim3(COOPB), dim3(BS), args, 0, stream);
  }

  // --- fused gather: pos/neg rows + both subgraph summaries in one CSR pass ---
  k_mega     <<<SUBB, BS, 0, stream>>>(rowptrD, colD, (const unsigned char*)FW,
                                       (const unsigned char*)FWn, keepPk, P, Q, sp1, sp2, N);
  k_reduce_s1<<<R1B, BS, 0, stream>>>(sp1, sp2, SUBB, R1ROWS, sp1b, sp2b);
  k_reduce_s2<<<1,   BS, 0, stream>>>(sp1b, sp2b, R1B, cf);
  k_sumv     <<<1, 64, 0, stream>>>(Wdisc, cf, C_SUM1, C_V1, 1.f/(float)target);
  k_sumv     <<<1, 64, 0, stream>>>(Wdisc, cf, C_SUM2, C_V2, 1.f/(float)target);

  // --- streaming loss ---
  k_loss2<<<NB, BS, 0, stream>>>(P, Q, cf, N);
  k_final<<<1, 1, 0, stream>>>(cf, out, N);
}

// Round 8
// 1145.153 us; speedup vs baseline: 2.2764x; 2.2764x over previous
//
#include <hip/hip_runtime.h>
#include <hip/hip_fp8.h>
#include <hip/hip_fp16.h>

#define BS 256
#define MAXIT 7
#define UNREACHED 0x3f3f3f3f
#define NPB 128          // nodes per scatter bucket (dst>>7)

// ctrl int-index layout (ctrl is 256B-aligned, 4096B)
#define C_DONE  0
#define C_CNT   1
#define C_BLKA  2
#define C_BLKB  3
#define C_BLKC  4
#define C_HSTAR 5
#define C_R     6
#define C_NEWA  8   // per-level newly-claimed slots, 8..8+MAXIT-1
#define C_LOSS  32  // float
#define C_SUM1  64  // float[64]
#define C_SUM2  128 // float[64]
#define C_V1    192 // float[64]
#define C_V2    256 // float[64]

typedef __hip_fp8_e4m3 fp8;

#define ALr(p)   __hip_atomic_load((p), __ATOMIC_RELAXED, __HIP_MEMORY_SCOPE_AGENT)
#define ASr(p,v) __hip_atomic_store((p),(v), __ATOMIC_RELAXED, __HIP_MEMORY_SCOPE_AGENT)
#define ASl(p,v) __hip_atomic_store((p),(v), __ATOMIC_RELEASE, __HIP_MEMORY_SCOPE_AGENT)

__device__ inline float softplusf(float x){
  return fmaxf(x, 0.f) + log1pf(expf(-fabsf(x)));
}

// ---------------- CSR build (in-edges only) ----------------
__global__ void k_deg1(const int* __restrict__ dst, int E, int* __restrict__ cnt){
  int i=blockIdx.x*BS+threadIdx.x, st=gridDim.x*BS;
  for(; i<E; i+=st) atomicAdd(&cnt[dst[i]],1);
}

__global__ void k_blocksum(const int* __restrict__ a, int n, int* __restrict__ part){
  __shared__ int s[BS];
  int t=threadIdx.x, i=blockIdx.x*BS+t;
  s[t] = (i<n)? a[i] : 0;
  __syncthreads();
  for(int o=BS/2;o>0;o>>=1){ if(t<o) s[t]+=s[t+o]; __syncthreads(); }
  if(t==0) part[blockIdx.x]=s[0];
}

// single-block parallel exclusive scan (in place), total at a[n]
__global__ void k_scan_block(int* a, int n){
  __shared__ int s[BS];
  __shared__ int carry;
  int t=threadIdx.x;
  if(t==0) carry=0;
  __syncthreads();
  for(int base=0; base<n; base+=BS){
    int i=base+t;
    int v=(i<n)? a[i] : 0;
    s[t]=v; __syncthreads();
    for(int o=1;o<BS;o<<=1){
      int x=(t>=o)? s[t-o]:0;
      __syncthreads();
      if(t>=o) s[t]+=x;
      __syncthreads();
    }
    if(i<n) a[i]=carry+s[t]-v;
    __syncthreads();
    if(t==0) carry+=s[BS-1];
    __syncthreads();
  }
  if(t==0) a[n]=carry;
}

__global__ void k_rowptr2(const int* __restrict__ cnt, const int* __restrict__ part, int n, int nb,
                          int* __restrict__ rowptr){
  __shared__ int s[BS];
  int b=blockIdx.x, t=threadIdx.x, i=b*BS+t;
  int v=(i<n)?cnt[i]:0;
  s[t]=v; __syncthreads();
  for(int o=1;o<BS;o<<=1){
    int x=(t>=o)? s[t-o]:0;
    __syncthreads();
    if(t>=o) s[t]+=x;
    __syncthreads();
  }
  if(i<n) rowptr[i]=s[t]-v+part[b];
  if(b==0&&t==0) rowptr[n]=part[nb];
}

__global__ void k_initbcur(const int* __restrict__ rowptr, int* __restrict__ bcur, int nbk){
  int i=blockIdx.x*BS+threadIdx.x;
  if(i<nbk) bcur[i]=rowptr[i*NPB];
}

// phase B: scatter (dst,src) pairs into bucket-contiguous regions (cursor-sequential writes)
__global__ void k_bscatter(const int* __restrict__ src, const int* __restrict__ dst, int E,
                           int* __restrict__ bcur, unsigned long long* __restrict__ pairs){
  int i=blockIdx.x*BS+threadIdx.x, st=gridDim.x*BS;
  for(; i<E; i+=st){
    int s=src[i], d=dst[i];
    int pos=atomicAdd(&bcur[d>>7],1);
    pairs[pos]=((unsigned long long)(unsigned)d<<32)|(unsigned)s;
  }
}

// phase C: one block per bucket, LDS cursors; final colD writes land in a small window
__global__ void k_bplace(const int* __restrict__ rowptr, const unsigned long long* __restrict__ pairs,
                         int* __restrict__ colD, int N){
  __shared__ int cur[NPB];
  int b=blockIdx.x, t=threadIdx.x;
  int v0=b*NPB, v1=min(v0+NPB,N);
  if(t<v1-v0) cur[t]=rowptr[v0+t];
  __syncthreads();
  int s0=rowptr[v0], e0=rowptr[v1];
  for(int i=s0+t; i<e0; i+=BS){
    unsigned long long p=pairs[i];
    int d=(int)(p>>32), s=(int)(p&0xffffffffu);
    int pos=atomicAdd(&cur[d-v0],1);
    colD[pos]=s;
  }
}

// ---------------- FW = feat @ W_enc  (fp8 e4m3 output) ----------------
__global__ void k_fw(const float* __restrict__ feat, const float* __restrict__ W,
                     fp8* __restrict__ FW, int N){
  __shared__ float sW[64*64];
  __shared__ float sf[4][64];
  int t=threadIdx.x;
  for(int i=t;i<64*64;i+=BS) sW[i]=W[i];
  __syncthreads();
  int j=t&63, r=t>>6;
  int ngroups=(N+3)>>2;
  for(int g=blockIdx.x; g<ngroups; g+=gridDim.x){
    int vr=g*4+r;
    sf[r][j] = (vr<N)? feat[vr*64+j] : 0.f;
    __syncthreads();
    if(vr<N){
      float acc=0.f;
      #pragma unroll
      for(int d=0;d<64;d++) acc += sf[r][d]*sW[d*64+j];
      FW[vr*64+j]=fp8(acc);
    }
    __syncthreads();
  }
}

// FWn[v] = FW[perm_neg[v]]
__global__ void k_permrows(const unsigned* __restrict__ FW, const int* __restrict__ pn,
                           unsigned* __restrict__ FWn, int N){
  int i=blockIdx.x*BS+threadIdx.x, st=gridDim.x*BS;
  int tot=N*16;
  for(; i<tot; i+=st){
    int v=i>>4, e=i&15;
    FWn[i]=FW[pn[v]*16+e];
  }
}

// ---------------- BFS (pull) ----------------
__global__ void k_bfs_init(int* __restrict__ hop, int N, const int* __restrict__ perm,
                           int* __restrict__ ctrl, int* __restrict__ hist,
                           unsigned* __restrict__ bits, int nw, int pi){
  int i=blockIdx.x*BS+threadIdx.x, st=gridDim.x*BS;
  int root=perm[0];
  for(int v=i;v<N;v+=st) hop[v]=(v==root)?0:UNREACHED;
  for(int k=i;k<nw;k+=st) bits[k]=0u;
  if(blockIdx.x==0){
    if(threadIdx.x<64) hist[threadIdx.x]=0;
    if(threadIdx.x==0){
      ctrl[C_DONE]=0; ctrl[C_CNT]=1;
      ctrl[C_BLKA]=0; ctrl[C_BLKB]=0; ctrl[C_BLKC]=0;
      for(int k=0;k<MAXIT;k++) ctrl[C_NEWA+k]=0;
      if(pi==0) ((float*)ctrl)[C_LOSS]=0.f;
    }
  }
}

// one launch per level; last-finishing block does bookkeeping (+rare stuck-seed)
__global__ void k_pull(const int* __restrict__ rowptr, const int* __restrict__ col,
                       int* __restrict__ hop, const int* __restrict__ perm,
                       int* __restrict__ ctrl, int it, int N, int target){
  if(ALr(&ctrl[C_DONE])) return;
  int t=threadIdx.x;
  int lvl=it+1;
  int bn=0;
  for(int v=blockIdx.x*BS+t; v<N; v+=gridDim.x*BS){
    if(hop[v]==UNREACHED){
      int b=rowptr[v], e=rowptr[v+1];
      for(int j=b;j<e;j++){
        int s=col[j];
        if(s==v) continue;                   // weight-0 self-loop
        if(hop[s]==lvl-1){ hop[v]=lvl; bn++; break; }
      }
    }
  }
  // block-sum of newly claimed
  __shared__ int sred[BS];
  sred[t]=bn; __syncthreads();
  for(int o=BS/2;o>0;o>>=1){ if(t<o) sred[t]+=sred[t+o]; __syncthreads(); }
  __shared__ int isLast, totNew;
  if(t==0){
    if(sred[0]) atomicAdd(&ctrl[C_NEWA+it], sred[0]);
    __threadfence();
    int tk=atomicAdd(&ctrl[C_BLKA],1);
    isLast=(tk==(int)gridDim.x-1);
  }
  __syncthreads();
  if(!isLast) return;
  __threadfence();
  if(t==0) totNew=ALr(&ctrl[C_NEWA+it]);
  __syncthreads();
  int newly=totNew;
  __shared__ int seeded;
  if(newly==0){
    // stuck: seed unreached node with min (perm,v) key
    __shared__ unsigned long long sk[BS];
    unsigned long long key=~0ull;
    for(int v=t; v<N; v+=BS)
      if(ALr(&hop[v])==UNREACHED){
        unsigned long long k=((unsigned long long)(unsigned)perm[v]<<32)|(unsigned)v;
        if(k<key)key=k;
      }
    sk[t]=key; __syncthreads();
    for(int o=BS/2;o>0;o>>=1){ if(t<o&&sk[t+o]<sk[t])sk[t]=sk[t+o]; __syncthreads(); }
    if(t==0){
      seeded=0;
      if(sk[0]!=~0ull){
        int idx=(int)(sk[0]&0xffffffffu);
        ASr(&hop[idx],lvl);
        seeded=1;
      }
    }
    __syncthreads();
    newly=seeded;
  }
  if(t==0){
    int c=ctrl[C_CNT]+newly;
    ctrl[C_CNT]=c;
    if(c>target) ASl(&ctrl[C_DONE],1);
    ASr(&ctrl[C_BLKA],0);
    __threadfence();
  }
}

// hop histogram + cutoff (ticket-fused)
__global__ void k_histcut(const int* __restrict__ hop, int N, int* __restrict__ hist,
                          int* __restrict__ ctrl, int target){
  __shared__ int lh[64];
  int t=threadIdx.x;
  if(t<64) lh[t]=0;
  __syncthreads();
  for(int v=blockIdx.x*BS+t; v<N; v+=gridDim.x*BS) atomicAdd(&lh[min(hop[v],63)],1);
  __syncthreads();
  if(t<64) atomicAdd(&hist[t], lh[t]);
  __shared__ int isLast;
  if(t==0){
    __threadfence();
    int tk=atomicAdd(&ctrl[C_BLKB],1);
    isLast=(tk==(int)gridDim.x-1);
  }
  __syncthreads();
  if(!isLast) return;
  if(t==0){
    __threadfence();
    int c=0,hstar=63,r=0;
    for(int h=0;h<64;h++){
      int x=ALr(&hist[h]);
      if(c+x>target){ hstar=h; r=target-c; break; }
      c+=x;
    }
    ctrl[C_HSTAR]=hstar; ctrl[C_R]=r;
    ASr(&ctrl[C_BLKB],0);
    __threadfence();
  }
}

// flag bits + word-popcount scan (ticket-fused)
__global__ void k_flagscan(const int* __restrict__ hop, const int* __restrict__ perm,
                           unsigned* __restrict__ bits, int* __restrict__ wordpref,
                           int N, int nw, int* __restrict__ ctrl){
  int t=threadIdx.x;
  int hstar=ctrl[C_HSTAR];
  for(int v=blockIdx.x*BS+t; v<N; v+=gridDim.x*BS)
    if(min(hop[v],63)==hstar){
      int p=perm[v];
      atomicOr(&bits[p>>5], 1u<<(p&31));
    }
  __shared__ int isLast;
  if(t==0){
    __threadfence();
    int tk=atomicAdd(&ctrl[C_BLKC],1);
    isLast=(tk==(int)gridDim.x-1);
  }
  __syncthreads();
  if(!isLast) return;
  __threadfence();
  // exclusive scan of per-word popcounts
  __shared__ int ss[BS];
  __shared__ int carry;
  if(t==0) carry=0;
  __syncthreads();
  for(int base=0; base<nw; base+=BS){
    int i=base+t;
    int v=(i<nw)? __popc(ALr(&bits[i])) : 0;
    ss[t]=v; __syncthreads();
    for(int o=1;o<BS;o<<=1){
      int x=(t>=o)? ss[t-o]:0;
      __syncthreads();
      if(t>=o) ss[t]+=x;
      __syncthreads();
    }
    if(i<nw) wordpref[i]=carry+ss[t]-v;
    __syncthreads();
    if(t==0) carry+=ss[BS-1];
    __syncthreads();
  }
  if(t==0){ ASr(&ctrl[C_BLKC],0); __threadfence(); }
}

__global__ void k_keep(const int* __restrict__ hop, const int* __restrict__ perm,
                       const unsigned* __restrict__ bits, const int* __restrict__ wordpref,
                       int* __restrict__ keepPk, int N, const int* __restrict__ ctrl, int pi){
  int hstar=ctrl[C_HSTAR], r=ctrl[C_R];
  int i=blockIdx.x*BS+threadIdx.x, st=gridDim.x*BS;
  for(int v=i;v<N;v+=st){
    int h=min(hop[v],63), kp=0;
    if(h<hstar) kp=1;
    else if(h==hstar){
      int p=perm[v];
      unsigned mask=(2u<<(p&31))-1u;
      int cum=wordpref[p>>5]+__popc(bits[p>>5]&mask);
      kp=(cum<=r);
    }
    if(pi==0) keepPk[v]=kp; else keepPk[v]|=kp<<1;
  }
}

// ---------------- fused mega gather: pos/neg rows + both subgraph summaries ----------------
__global__ void __launch_bounds__(BS, 8) k_mega(
    const int* __restrict__ rowptr, const int* __restrict__ col,
    const unsigned char* __restrict__ FW8, const unsigned char* __restrict__ FWn8,
    const int* __restrict__ keepPk,
    __half* __restrict__ P, __half* __restrict__ Q,
    float* __restrict__ sp1, float* __restrict__ sp2, int N){
  __shared__ uint4 ldsA4[4][16][4];
  __shared__ uint4 ldsB4[4][16][4];
  __shared__ float sh1[4][64], sh2[4][64];
  int t=threadIdx.x, lane=t&63, w=t>>6;
  int eidx=lane>>2, q=lane&3;
  volatile unsigned char* lA=(volatile unsigned char*)&ldsA4[w][0][0];
  volatile unsigned char* lB=(volatile unsigned char*)&ldsB4[w][0][0];
  int wid=(blockIdx.x*BS+t)>>6, nw=(gridDim.x*BS)>>6;
  float acc1=0.f, acc2=0.f;
  for(int v=wid; v<N; v+=nw){
    int b=rowptr[v], e=rowptr[v+1];
    int deg=e-b;
    int kv=keepPk[v];
    float ap=0.f, an=0.f, a1=0.f, a2=0.f;
    int c1t=0, c2t=0;
    for(int c0=b; c0<e; c0+=16){
      int n=min(16, e-c0);
      uint4 wa=make_uint4(0,0,0,0), wb=make_uint4(0,0,0,0);
      int kk=0;
      if(eidx<n){
        int s=col[c0+eidx];
        kk=keepPk[s];
        size_t off=((size_t)s<<6)+(q<<4);
        wa=*reinterpret_cast<const uint4*>(FW8+off);
        wb=*reinterpret_cast<const uint4*>(FWn8+off);
      }
      volatile unsigned* pa=(volatile unsigned*)&ldsA4[w][eidx][q];
      volatile unsigned* pb=(volatile unsigned*)&ldsB4[w][eidx][q];
      pa[0]=wa.x; pa[1]=wa.y; pa[2]=wa.z; pa[3]=wa.w;
      pb[0]=wb.x; pb[1]=wb.y; pb[2]=wb.z; pb[3]=wb.w;
      unsigned long long bal1=__ballot(q==0 && (kk&1));
      unsigned long long bal2=__ballot(q==0 && (kk&2));
      c1t+=__popcll(bal1); c2t+=__popcll(bal2);
      if(n==16){
        #pragma unroll
        for(int ee=0; ee<16; ee++){
          fp8 ha, hb;
          ha.__x=lA[ee*64+lane];
          hb.__x=lB[ee*64+lane];
          float fa=(float)ha, fb=(float)hb;
          ap+=fa; an+=fb;
          a1 += ((bal1>>(ee*4))&1) ? fa : 0.f;
          a2 += ((bal2>>(ee*4))&1) ? fa : 0.f;
        }
      } else {
        for(int ee=0; ee<n; ee++){
          fp8 ha, hb;
          ha.__x=lA[ee*64+lane];
          hb.__x=lB[ee*64+lane];
          float fa=(float)ha, fb=(float)hb;
          ap+=fa; an+=fb;
          a1 += ((bal1>>(ee*4))&1) ? fa : 0.f;
          a2 += ((bal2>>(ee*4))&1) ? fa : 0.f;
        }
      }
    }
    float invd=1.f/(float)deg;
    float p =fmaxf(ap*invd, 0.f);
    float qq=fmaxf(an*invd, 0.f);
    P[(size_t)v*64+lane]=__float2half(p);
    Q[(size_t)v*64+lane]=__float2half(qq);
    if(kv&1) acc1+=fmaxf(a1/(float)max(c1t,1), 0.f);
    if(kv&2) acc2+=fmaxf(a2/(float)max(c2t,1), 0.f);
  }
  sh1[w][lane]=acc1; sh2[w][lane]=acc2;
  __syncthreads();
  if(w==0){
    sp1[blockIdx.x*64+lane]=sh1[0][lane]+sh1[1][lane]+sh1[2][lane]+sh1[3][lane];
    sp2[blockIdx.x*64+lane]=sh2[0][lane]+sh2[1][lane]+sh2[2][lane]+sh2[3][lane];
  }
}

__global__ void k_reduce_s1(const float* __restrict__ sp1, const float* __restrict__ sp2,
                            int nb, int rows, float* __restrict__ sp1b, float* __restrict__ sp2b){
  __shared__ float s[BS];
  int t=threadIdx.x, lane=t&63, p=t>>6;
  int base=blockIdx.x*rows;
  float a=0.f;
  for(int r=p; r<rows; r+=4){
    int row=base+r;
    if(row<nb) a+=sp1[row*64+lane];
  }
  s[t]=a; __syncthreads();
  if(t<64) sp1b[blockIdx.x*64+t]=s[t]+s[t+64]+s[t+128]+s[t+192];
  __syncthreads();
  a=0.f;
  for(int r=p; r<rows; r+=4){
    int row=base+r;
    if(row<nb) a+=sp2[row*64+lane];
  }
  s[t]=a; __syncthreads();
  if(t<64) sp2b[blockIdx.x*64+t]=s[t]+s[t+64]+s[t+128]+s[t+192];
}

__global__ void k_reduce_s2(const float* __restrict__ sp1b, const float* __restrict__ sp2b,
                            int nb2, float* __restrict__ cf){
  __shared__ float s[BS];
  int t=threadIdx.x, lane=t&63, p=t>>6;
  float a=0.f;
  for(int b=p;b<nb2;b+=4) a+=sp1b[b*64+lane];
  s[t]=a; __syncthreads();
  if(t<64) cf[C_SUM1+t]=s[t]+s[t+64]+s[t+128]+s[t+192];
  __syncthreads();
  a=0.f;
  for(int b=p;b<nb2;b+=4) a+=sp2b[b*64+lane];
  s[t]=a; __syncthreads();
  if(t<64) cf[C_SUM2+t]=s[t]+s[t+64]+s[t+128]+s[t+192];
}

__global__ void k_sumv(const float* __restrict__ Wd, float* __restrict__ cf,
                       int sumoff, int voff, float invk){
  __shared__ float s[64];
  int t=threadIdx.x;
  if(t<64){
    float x=cf[sumoff+t]*invk;
    s[t]=1.f/(1.f+expf(-x));
  }
  __syncthreads();
  if(t<64){
    float a=0.f;
    #pragma unroll
    for(int d=0;d<64;d++) a+=Wd[t*64+d]*s[d];
    cf[voff+t]=a;
  }
}

__global__ void k_loss2(const __half* __restrict__ P, const __half* __restrict__ Q,
                        float* __restrict__ cf, int N){
  __shared__ float sv1[64], sv2[64];
  __shared__ float sred[BS];
  int t=threadIdx.x;
  if(t<64){ sv1[t]=cf[C_V1+t]; sv2[t]=cf[C_V2+t]; }
  __syncthreads();
  int i=blockIdx.x*BS+t, st=gridDim.x*BS;
  float acc=0.f;
  for(int v=i; v<N; v+=st){
    const uint4* pr=(const uint4*)(P+(size_t)v*64);
    const uint4* qr=(const uint4*)(Q+(size_t)v*64);
    float a1=0.f,a2=0.f,b1=0.f,b2=0.f;
    #pragma unroll
    for(int c=0;c<8;c++){
      uint4 pu=pr[c], qu=qr[c];
      unsigned arr[4]={pu.x,pu.y,pu.z,pu.w};
      unsigned brr[4]={qu.x,qu.y,qu.z,qu.w};
      #pragma unroll
      for(int j=0;j<4;j++){
        int d=c*8+j*2;
        __half2 ph=*(const __half2*)&arr[j];
        __half2 qh=*(const __half2*)&brr[j];
        float2 pf=__half22float2(ph);
        float2 qf=__half22float2(qh);
        a1=fmaf(pf.x,sv1[d],a1); a1=fmaf(pf.y,sv1[d+1],a1);
        a2=fmaf(pf.x,sv2[d],a2); a2=fmaf(pf.y,sv2[d+1],a2);
        b1=fmaf(qf.x,sv1[d],b1); b1=fmaf(qf.y,sv1[d+1],b1);
        b2=fmaf(qf.x,sv2[d],b2); b2=fmaf(qf.y,sv2[d+1],b2);
      }
    }
    acc += softplusf(-a1)+softplusf(b1)+softplusf(-a2)+softplusf(b2);
  }
  sred[t]=acc;
  __syncthreads();
  for(int o=BS/2;o>0;o>>=1){ if(t<o) sred[t]+=sred[t+o]; __syncthreads(); }
  if(t==0) atomicAdd(&cf[C_LOSS], sred[0]);
}

__global__ void k_final(const float* __restrict__ cf, float* __restrict__ out, int N){
  if(blockIdx.x||threadIdx.x) return;
  out[0]=cf[C_LOSS]/(float)N;
}

extern "C" void kernel_launch(void* const* d_in, const int* in_sizes, int n_in,
                              void* d_out, int out_size, void* d_ws, size_t ws_size,
                              hipStream_t stream) {
  const float* feat    = (const float*)d_in[0];
  const float* Wenc    = (const float*)d_in[1];
  const float* Wdisc   = (const float*)d_in[2];
  const int*   src     = (const int*)d_in[3];
  const int*   dst     = (const int*)d_in[4];
  const int*   permneg = (const int*)d_in[5];
  const int*   perm1   = (const int*)d_in[6];
  const int*   perm2   = (const int*)d_in[7];
  float* out = (float*)d_out;

  int N = in_sizes[5];
  int E = in_sizes[3];
  int target = (int)((double)N*0.8);
  int NB = (N+BS-1)/BS;
  int WORDS = (N+31)/32;
  int NBK = (N+NPB-1)/NPB;
  int gE = (E+BS-1)/BS; if(gE>4096) gE=4096;
  const int SUBB = 2048;
  const int R1B = 128, R1ROWS = SUBB/R1B;

  // workspace carve (256B-aligned chunks)
  char* w = (char*)d_ws;
  auto alloc = [&](size_t bytes)->void*{
    void* p = (void*)w;
    w += (bytes + 255) & ~(size_t)255;
    return p;
  };
  size_t szN = ((size_t)N*4 + 255) & ~(size_t)255;
  int*      ctrl    = (int*)     alloc(4096);
  int*      cntD    = (int*)     alloc(szN);
  int*      rowptrD = (int*)     alloc((size_t)(N+1)*4);
  int*      bcur    = (int*)     alloc((size_t)NBK*4);
  int*      colD    = (int*)     alloc((size_t)E*4);
  unsigned long long* pairs = (unsigned long long*)alloc((size_t)E*8);
  int*      hop     = (int*)     alloc((size_t)N*4);
  int*      keepPk  = (int*)     alloc((size_t)N*4);
  unsigned* bits    = (unsigned*)alloc((size_t)WORDS*4);
  int*      wordpref= (int*)     alloc((size_t)(WORDS+1)*4);
  int*      part    = (int*)     alloc((size_t)(NB+2)*4);
  int*      hist    = (int*)     alloc(64*4);
  fp8*      FW      = (fp8*)     alloc((size_t)N*64);
  fp8*      FWn     = (fp8*)     alloc((size_t)N*64);
  __half*   P       = (__half*)  alloc((size_t)N*64*2);
  __half*   Q       = (__half*)  alloc((size_t)N*64*2);
  float*    sp1     = (float*)   alloc((size_t)SUBB*64*4);
  float*    sp2     = (float*)   alloc((size_t)SUBB*64*4);
  float*    sp1b    = (float*)   alloc((size_t)R1B*64*4);
  float*    sp2b    = (float*)   alloc((size_t)R1B*64*4);
  float*    cf = (float*)ctrl;

  // --- build in-CSR via bucketed scatter ---
  hipMemsetAsync(cntD, 0, szN, stream);
  k_deg1      <<<gE, BS, 0, stream>>>(dst, E, cntD);
  k_blocksum  <<<NB, BS, 0, stream>>>(cntD, N, part);
  k_scan_block<<<1,  BS, 0, stream>>>(part, NB);
  k_rowptr2   <<<NB, BS, 0, stream>>>(cntD, part, N, NB, rowptrD);
  k_initbcur  <<<(NBK+BS-1)/BS, BS, 0, stream>>>(rowptrD, bcur, NBK);
  k_bscatter  <<<gE, BS, 0, stream>>>(src, dst, E, bcur, pairs);
  k_bplace    <<<NBK, BS, 0, stream>>>(rowptrD, pairs, colD, N);

  // --- FW = feat @ W_enc (fp8), FWn = FW[perm_neg] ---
  k_fw      <<<2048, BS, 0, stream>>>(feat, Wenc, FW, N);
  k_permrows<<<4096, BS, 0, stream>>>((const unsigned*)FW, permneg, (unsigned*)FWn, N);

  // --- per-perm: pull BFS + keep mask ---
  const int* perms[2] = {perm1, perm2};
  for(int pi=0; pi<2; pi++){
    const int* perm = perms[pi];
    k_bfs_init<<<NB, BS, 0, stream>>>(hop, N, perm, ctrl, hist, bits, WORDS, pi);
    for(int it=0; it<MAXIT; it++)
      k_pull<<<NB, BS, 0, stream>>>(rowptrD, colD, hop, perm, ctrl, it, N, target);
    k_histcut <<<NB, BS, 0, stream>>>(hop, N, hist, ctrl, target);
    k_flagscan<<<NB, BS, 0, stream>>>(hop, perm, bits, wordpref, N, WORDS, ctrl);
    k_keep    <<<NB, BS, 0, stream>>>(hop, perm, bits, wordpref, keepPk, N, ctrl, pi);
  }

  // --- fused gather: pos/neg rows + both subgraph summaries in one CSR pass ---
  k_mega     <<<SUBB, BS, 0, stream>>>(rowptrD, colD, (const unsigned char*)FW,
                                       (const unsigned char*)FWn, keepPk, P, Q, sp1, sp2, N);
  k_reduce_s1<<<R1B, BS, 0, stream>>>(sp1, sp2, SUBB, R1ROWS, sp1b, sp2b);
  k_reduce_s2<<<1,   BS, 0, stream>>>(sp1b, sp2b, R1B, cf);
  k_sumv     <<<1, 64, 0, stream>>>(Wdisc, cf, C_SUM1, C_V1, 1.f/(float)target);
  k_sumv     <<<1, 64, 0, stream>>>(Wdisc, cf, C_SUM2, C_V2, 1.f/(float)target);

  // --- streaming loss ---
  k_loss2<<<NB, BS, 0, stream>>>(P, Q, cf, N);
  k_final<<<1, 1, 0, stream>>>(cf, out, N);
}

// Round 9
// 789.430 us; speedup vs baseline: 3.3021x; 1.4506x over previous
//
#include <hip/hip_runtime.h>
#include <hip/hip_fp8.h>
#include <hip/hip_fp16.h>

#define BS 256
#define MAXIT 7
#define UNREACHED 0x3f3f3f3f
#define NR 256           // nodes per radix bucket (dst>>8)
#define RB 64            // edge blocks for radix passes

// ctrl int-index layout (ctrl is 256B-aligned, 4096B)
#define C_DONE  0
#define C_CNT   1
#define C_BLKA  2
#define C_BLKB  3
#define C_BLKC  4
#define C_HSTAR 5
#define C_R     6
#define C_NEWA  8   // per-level newly-claimed slots, 8..8+MAXIT-1
#define C_LOSS  32  // float
#define C_SUM1  64  // float[64]
#define C_SUM2  128 // float[64]
#define C_V1    192 // float[64]
#define C_V2    256 // float[64]

typedef __hip_fp8_e4m3 fp8;

#define ALr(p)   __hip_atomic_load((p), __ATOMIC_RELAXED, __HIP_MEMORY_SCOPE_AGENT)
#define ASr(p,v) __hip_atomic_store((p),(v), __ATOMIC_RELAXED, __HIP_MEMORY_SCOPE_AGENT)
#define ASl(p,v) __hip_atomic_store((p),(v), __ATOMIC_RELEASE, __HIP_MEMORY_SCOPE_AGENT)

__device__ inline float softplusf(float x){
  return fmaxf(x, 0.f) + log1pf(expf(-fabsf(x)));
}

// ---------------- CSR build (in-edges only, radix-partitioned) ----------------
__global__ void k_deg1(const int* __restrict__ dst, int E, int* __restrict__ cnt){
  int i=blockIdx.x*BS+threadIdx.x, st=gridDim.x*BS;
  for(; i<E; i+=st) atomicAdd(&cnt[dst[i]],1);
}

__global__ void k_blocksum(const int* __restrict__ a, int n, int* __restrict__ part){
  __shared__ int s[BS];
  int t=threadIdx.x, i=blockIdx.x*BS+t;
  s[t] = (i<n)? a[i] : 0;
  __syncthreads();
  for(int o=BS/2;o>0;o>>=1){ if(t<o) s[t]+=s[t+o]; __syncthreads(); }
  if(t==0) part[blockIdx.x]=s[0];
}

__global__ void k_scan_block(int* a, int n){
  __shared__ int s[BS];
  __shared__ int carry;
  int t=threadIdx.x;
  if(t==0) carry=0;
  __syncthreads();
  for(int base=0; base<n; base+=BS){
    int i=base+t;
    int v=(i<n)? a[i] : 0;
    s[t]=v; __syncthreads();
    for(int o=1;o<BS;o<<=1){
      int x=(t>=o)? s[t-o]:0;
      __syncthreads();
      if(t>=o) s[t]+=x;
      __syncthreads();
    }
    if(i<n) a[i]=carry+s[t]-v;
    __syncthreads();
    if(t==0) carry+=s[BS-1];
    __syncthreads();
  }
  if(t==0) a[n]=carry;
}

__global__ void k_rowptr2(const int* __restrict__ cnt, const int* __restrict__ part, int n, int nb,
                          int* __restrict__ rowptr){
  __shared__ int s[BS];
  int b=blockIdx.x, t=threadIdx.x, i=b*BS+t;
  int v=(i<n)?cnt[i]:0;
  s[t]=v; __syncthreads();
  for(int o=1;o<BS;o<<=1){
    int x=(t>=o)? s[t-o]:0;
    __syncthreads();
    if(t>=o) s[t]+=x;
    __syncthreads();
  }
  if(i<n) rowptr[i]=s[t]-v+part[b];
  if(b==0&&t==0) rowptr[n]=part[nb];
}

// radix pass 1: per-edge-block LDS histogram by dst>>8
__global__ void k_rhist(const int* __restrict__ dst, int E,
                        int* __restrict__ hist, int nbk){
  __shared__ int lh[512];
  int b=blockIdx.x, t=threadIdx.x;
  for(int i=t;i<nbk;i+=BS) lh[i]=0;
  __syncthreads();
  int per=(E+RB-1)/RB;
  int s0=b*per, s1=min(s0+per,E);
  for(int i=s0+t;i<s1;i+=BS) atomicAdd(&lh[dst[i]>>8],1);
  __syncthreads();
  for(int i=t;i<nbk;i+=BS) hist[b*nbk+i]=lh[i];
}

// radix pass 2: place (dst,src) pairs at private per-(block,bucket) cursors (LDS only)
__global__ void k_rscatter(const int* __restrict__ src, const int* __restrict__ dst, int E,
                           const int* __restrict__ hist, const int* __restrict__ rowptr,
                           unsigned long long* __restrict__ pairs, int nbk, int N){
  __shared__ int cur[512];
  int b=blockIdx.x, t=threadIdx.x;
  for(int r=t; r<nbk; r+=BS){
    int off=rowptr[r*NR];                       // bucket base in final CSR layout
    for(int bb=0; bb<b; bb++) off += hist[bb*nbk+r];
    cur[r]=off;
  }
  __syncthreads();
  int per=(E+RB-1)/RB;
  int s0=b*per, s1=min(s0+per,E);
  for(int i=s0+t;i<s1;i+=BS){
    int s=src[i], d=dst[i];
    int pos=atomicAdd(&cur[d>>8],1);
    pairs[pos]=((unsigned long long)(unsigned)d<<32)|(unsigned)s;
  }
}

// pass 3: one block per 256-node bucket; LDS cursors; colD writes land in a small window
__global__ void k_bplace(const int* __restrict__ rowptr, const unsigned long long* __restrict__ pairs,
                         int* __restrict__ colD, int N){
  __shared__ int cur[NR];
  int b=blockIdx.x, t=threadIdx.x;
  int v0=b*NR, v1=min(v0+NR,N);
  if(t<v1-v0) cur[t]=rowptr[v0+t];
  __syncthreads();
  int s0=rowptr[v0], e0=rowptr[v1];
  for(int i=s0+t; i<e0; i+=BS){
    unsigned long long p=pairs[i];
    int d=(int)(p>>32), s=(int)(p&0xffffffffu);
    int pos=atomicAdd(&cur[d-v0],1);
    colD[pos]=s;
  }
}

// ---------------- FW = feat @ W_enc  (fp8 e4m3 output) ----------------
__global__ void k_fw(const float* __restrict__ feat, const float* __restrict__ W,
                     fp8* __restrict__ FW, int N){
  __shared__ float sW[64*64];
  __shared__ float sf[4][64];
  int t=threadIdx.x;
  for(int i=t;i<64*64;i+=BS) sW[i]=W[i];
  __syncthreads();
  int j=t&63, r=t>>6;
  int ngroups=(N+3)>>2;
  for(int g=blockIdx.x; g<ngroups; g+=gridDim.x){
    int vr=g*4+r;
    sf[r][j] = (vr<N)? feat[vr*64+j] : 0.f;
    __syncthreads();
    if(vr<N){
      float acc=0.f;
      #pragma unroll
      for(int d=0;d<64;d++) acc += sf[r][d]*sW[d*64+j];
      FW[vr*64+j]=fp8(acc);
    }
    __syncthreads();
  }
}

// FWn[v] = FW[perm_neg[v]]
__global__ void k_permrows(const unsigned* __restrict__ FW, const int* __restrict__ pn,
                           unsigned* __restrict__ FWn, int N){
  int i=blockIdx.x*BS+threadIdx.x, st=gridDim.x*BS;
  int tot=N*16;
  for(; i<tot; i+=st){
    int v=i>>4, e=i&15;
    FWn[i]=FW[pn[v]*16+e];
  }
}

// ---------------- BFS (pull) ----------------
__global__ void k_bfs_init(int* __restrict__ hop, int N, const int* __restrict__ perm,
                           int* __restrict__ ctrl, int* __restrict__ hist,
                           unsigned* __restrict__ bits, int nw, int pi){
  int i=blockIdx.x*BS+threadIdx.x, st=gridDim.x*BS;
  int root=perm[0];
  for(int v=i;v<N;v+=st) hop[v]=(v==root)?0:UNREACHED;
  for(int k=i;k<nw;k+=st) bits[k]=0u;
  if(blockIdx.x==0){
    if(threadIdx.x<64) hist[threadIdx.x]=0;
    if(threadIdx.x==0){
      ctrl[C_DONE]=0; ctrl[C_CNT]=1;
      ctrl[C_BLKA]=0; ctrl[C_BLKB]=0; ctrl[C_BLKC]=0;
      for(int k=0;k<MAXIT;k++) ctrl[C_NEWA+k]=0;
      if(pi==0) ((float*)ctrl)[C_LOSS]=0.f;
    }
  }
}

// one launch per level; last-finishing block does bookkeeping (+rare stuck-seed)
__global__ void k_pull(const int* __restrict__ rowptr, const int* __restrict__ col,
                       int* __restrict__ hop, const int* __restrict__ perm,
                       int* __restrict__ ctrl, int it, int N, int target){
  if(ALr(&ctrl[C_DONE])) return;
  int t=threadIdx.x;
  int lvl=it+1;
  int bn=0;
  for(int v=blockIdx.x*BS+t; v<N; v+=gridDim.x*BS){
    if(hop[v]==UNREACHED){
      int b=rowptr[v], e=rowptr[v+1];
      for(int j=b;j<e;j++){
        int s=col[j];
        if(s==v) continue;                   // weight-0 self-loop
        if(hop[s]==lvl-1){ hop[v]=lvl; bn++; break; }
      }
    }
  }
  __shared__ int sred[BS];
  sred[t]=bn; __syncthreads();
  for(int o=BS/2;o>0;o>>=1){ if(t<o) sred[t]+=sred[t+o]; __syncthreads(); }
  __shared__ int isLast, totNew;
  if(t==0){
    if(sred[0]) atomicAdd(&ctrl[C_NEWA+it], sred[0]);
    __threadfence();
    int tk=atomicAdd(&ctrl[C_BLKA],1);
    isLast=(tk==(int)gridDim.x-1);
  }
  __syncthreads();
  if(!isLast) return;
  __threadfence();
  if(t==0) totNew=ALr(&ctrl[C_NEWA+it]);
  __syncthreads();
  int newly=totNew;
  __shared__ int seeded;
  if(newly==0){
    __shared__ unsigned long long sk[BS];
    unsigned long long key=~0ull;
    for(int v=t; v<N; v+=BS)
      if(ALr(&hop[v])==UNREACHED){
        unsigned long long k=((unsigned long long)(unsigned)perm[v]<<32)|(unsigned)v;
        if(k<key)key=k;
      }
    sk[t]=key; __syncthreads();
    for(int o=BS/2;o>0;o>>=1){ if(t<o&&sk[t+o]<sk[t])sk[t]=sk[t+o]; __syncthreads(); }
    if(t==0){
      seeded=0;
      if(sk[0]!=~0ull){
        int idx=(int)(sk[0]&0xffffffffu);
        ASr(&hop[idx],lvl);
        seeded=1;
      }
    }
    __syncthreads();
    newly=seeded;
  }
  if(t==0){
    int c=ctrl[C_CNT]+newly;
    ctrl[C_CNT]=c;
    if(c>target) ASl(&ctrl[C_DONE],1);
    ASr(&ctrl[C_BLKA],0);
    __threadfence();
  }
}

// hop histogram + cutoff (ticket-fused)
__global__ void k_histcut(const int* __restrict__ hop, int N, int* __restrict__ hist,
                          int* __restrict__ ctrl, int target){
  __shared__ int lh[64];
  int t=threadIdx.x;
  if(t<64) lh[t]=0;
  __syncthreads();
  for(int v=blockIdx.x*BS+t; v<N; v+=gridDim.x*BS) atomicAdd(&lh[min(hop[v],63)],1);
  __syncthreads();
  if(t<64) atomicAdd(&hist[t], lh[t]);
  __shared__ int isLast;
  if(t==0){
    __threadfence();
    int tk=atomicAdd(&ctrl[C_BLKB],1);
    isLast=(tk==(int)gridDim.x-1);
  }
  __syncthreads();
  if(!isLast) return;
  if(t==0){
    __threadfence();
    int c=0,hstar=63,r=0;
    for(int h=0;h<64;h++){
      int x=ALr(&hist[h]);
      if(c+x>target){ hstar=h; r=target-c; break; }
      c+=x;
    }
    ctrl[C_HSTAR]=hstar; ctrl[C_R]=r;
    ASr(&ctrl[C_BLKB],0);
    __threadfence();
  }
}

// flag bits + word-popcount scan (ticket-fused)
__global__ void k_flagscan(const int* __restrict__ hop, const int* __restrict__ perm,
                           unsigned* __restrict__ bits, int* __restrict__ wordpref,
                           int N, int nw, int* __restrict__ ctrl){
  int t=threadIdx.x;
  int hstar=ctrl[C_HSTAR];
  for(int v=blockIdx.x*BS+t; v<N; v+=gridDim.x*BS)
    if(min(hop[v],63)==hstar){
      int p=perm[v];
      atomicOr(&bits[p>>5], 1u<<(p&31));
    }
  __shared__ int isLast;
  if(t==0){
    __threadfence();
    int tk=atomicAdd(&ctrl[C_BLKC],1);
    isLast=(tk==(int)gridDim.x-1);
  }
  __syncthreads();
  if(!isLast) return;
  __threadfence();
  __shared__ int ss[BS];
  __shared__ int carry;
  if(t==0) carry=0;
  __syncthreads();
  for(int base=0; base<nw; base+=BS){
    int i=base+t;
    int v=(i<nw)? __popc(ALr(&bits[i])) : 0;
    ss[t]=v; __syncthreads();
    for(int o=1;o<BS;o<<=1){
      int x=(t>=o)? ss[t-o]:0;
      __syncthreads();
      if(t>=o) ss[t]+=x;
      __syncthreads();
    }
    if(i<nw) wordpref[i]=carry+ss[t]-v;
    __syncthreads();
    if(t==0) carry+=ss[BS-1];
    __syncthreads();
  }
  if(t==0){ ASr(&ctrl[C_BLKC],0); __threadfence(); }
}

__global__ void k_keep(const int* __restrict__ hop, const int* __restrict__ perm,
                       const unsigned* __restrict__ bits, const int* __restrict__ wordpref,
                       int* __restrict__ keepPk, int N, const int* __restrict__ ctrl, int pi){
  int hstar=ctrl[C_HSTAR], r=ctrl[C_R];
  int i=blockIdx.x*BS+threadIdx.x, st=gridDim.x*BS;
  for(int v=i;v<N;v+=st){
    int h=min(hop[v],63), kp=0;
    if(h<hstar) kp=1;
    else if(h==hstar){
      int p=perm[v];
      unsigned mask=(2u<<(p&31))-1u;
      int cum=wordpref[p>>5]+__popc(bits[p>>5]&mask);
      kp=(cum<=r);
    }
    if(pi==0) keepPk[v]=kp; else keepPk[v]|=kp<<1;
  }
}

// ---------------- fused mega gather: pos/neg rows + both subgraph summaries ----------------
__global__ void __launch_bounds__(BS, 8) k_mega(
    const int* __restrict__ rowptr, const int* __restrict__ col,
    const unsigned char* __restrict__ FW8, const unsigned char* __restrict__ FWn8,
    const int* __restrict__ keepPk,
    __half* __restrict__ P, __half* __restrict__ Q,
    float* __restrict__ sp1, float* __restrict__ sp2, int N){
  __shared__ uint4 ldsA4[4][16][4];
  __shared__ uint4 ldsB4[4][16][4];
  __shared__ float sh1[4][64], sh2[4][64];
  int t=threadIdx.x, lane=t&63, w=t>>6;
  int eidx=lane>>2, q=lane&3;
  volatile unsigned char* lA=(volatile unsigned char*)&ldsA4[w][0][0];
  volatile unsigned char* lB=(volatile unsigned char*)&ldsB4[w][0][0];
  int wid=(blockIdx.x*BS+t)>>6, nw=(gridDim.x*BS)>>6;
  float acc1=0.f, acc2=0.f;
  for(int v=wid; v<N; v+=nw){
    int b=rowptr[v], e=rowptr[v+1];
    int deg=e-b;
    int kv=keepPk[v];
    float ap=0.f, an=0.f, a1=0.f, a2=0.f;
    int c1t=0, c2t=0;
    for(int c0=b; c0<e; c0+=16){
      int n=min(16, e-c0);
      uint4 wa=make_uint4(0,0,0,0), wb=make_uint4(0,0,0,0);
      int kk=0;
      if(eidx<n){
        int s=col[c0+eidx];
        kk=keepPk[s];
        size_t off=((size_t)s<<6)+(q<<4);
        wa=*reinterpret_cast<const uint4*>(FW8+off);
        wb=*reinterpret_cast<const uint4*>(FWn8+off);
      }
      volatile unsigned* pa=(volatile unsigned*)&ldsA4[w][eidx][q];
      volatile unsigned* pb=(volatile unsigned*)&ldsB4[w][eidx][q];
      pa[0]=wa.x; pa[1]=wa.y; pa[2]=wa.z; pa[3]=wa.w;
      pb[0]=wb.x; pb[1]=wb.y; pb[2]=wb.z; pb[3]=wb.w;
      unsigned long long bal1=__ballot(q==0 && (kk&1));
      unsigned long long bal2=__ballot(q==0 && (kk&2));
      c1t+=__popcll(bal1); c2t+=__popcll(bal2);
      if(n==16){
        #pragma unroll
        for(int ee=0; ee<16; ee++){
          fp8 ha, hb;
          ha.__x=lA[ee*64+lane];
          hb.__x=lB[ee*64+lane];
          float fa=(float)ha, fb=(float)hb;
          ap+=fa; an+=fb;
          a1 += ((bal1>>(ee*4))&1) ? fa : 0.f;
          a2 += ((bal2>>(ee*4))&1) ? fa : 0.f;
        }
      } else {
        for(int ee=0; ee<n; ee++){
          fp8 ha, hb;
          ha.__x=lA[ee*64+lane];
          hb.__x=lB[ee*64+lane];
          float fa=(float)ha, fb=(float)hb;
          ap+=fa; an+=fb;
          a1 += ((bal1>>(ee*4))&1) ? fa : 0.f;
          a2 += ((bal2>>(ee*4))&1) ? fa : 0.f;
        }
      }
    }
    float invd=1.f/(float)deg;
    float p =fmaxf(ap*invd, 0.f);
    float qq=fmaxf(an*invd, 0.f);
    P[(size_t)v*64+lane]=__float2half(p);
    Q[(size_t)v*64+lane]=__float2half(qq);
    if(kv&1) acc1+=fmaxf(a1/(float)max(c1t,1), 0.f);
    if(kv&2) acc2+=fmaxf(a2/(float)max(c2t,1), 0.f);
  }
  sh1[w][lane]=acc1; sh2[w][lane]=acc2;
  __syncthreads();
  if(w==0){
    sp1[blockIdx.x*64+lane]=sh1[0][lane]+sh1[1][lane]+sh1[2][lane]+sh1[3][lane];
    sp2[blockIdx.x*64+lane]=sh2[0][lane]+sh2[1][lane]+sh2[2][lane]+sh2[3][lane];
  }
}

__global__ void k_reduce_s1(const float* __restrict__ sp1, const float* __restrict__ sp2,
                            int nb, int rows, float* __restrict__ sp1b, float* __restrict__ sp2b){
  __shared__ float s[BS];
  int t=threadIdx.x, lane=t&63, p=t>>6;
  int base=blockIdx.x*rows;
  float a=0.f;
  for(int r=p; r<rows; r+=4){
    int row=base+r;
    if(row<nb) a+=sp1[row*64+lane];
  }
  s[t]=a; __syncthreads();
  if(t<64) sp1b[blockIdx.x*64+t]=s[t]+s[t+64]+s[t+128]+s[t+192];
  __syncthreads();
  a=0.f;
  for(int r=p; r<rows; r+=4){
    int row=base+r;
    if(row<nb) a+=sp2[row*64+lane];
  }
  s[t]=a; __syncthreads();
  if(t<64) sp2b[blockIdx.x*64+t]=s[t]+s[t+64]+s[t+128]+s[t+192];
}

__global__ void k_reduce_s2(const float* __restrict__ sp1b, const float* __restrict__ sp2b,
                            int nb2, float* __restrict__ cf){
  __shared__ float s[BS];
  int t=threadIdx.x, lane=t&63, p=t>>6;
  float a=0.f;
  for(int b=p;b<nb2;b+=4) a+=sp1b[b*64+lane];
  s[t]=a; __syncthreads();
  if(t<64) cf[C_SUM1+t]=s[t]+s[t+64]+s[t+128]+s[t+192];
  __syncthreads();
  a=0.f;
  for(int b=p;b<nb2;b+=4) a+=sp2b[b*64+lane];
  s[t]=a; __syncthreads();
  if(t<64) cf[C_SUM2+t]=s[t]+s[t+64]+s[t+128]+s[t+192];
}

__global__ void k_sumv(const float* __restrict__ Wd, float* __restrict__ cf,
                       int sumoff, int voff, float invk){
  __shared__ float s[64];
  int t=threadIdx.x;
  if(t<64){
    float x=cf[sumoff+t]*invk;
    s[t]=1.f/(1.f+expf(-x));
  }
  __syncthreads();
  if(t<64){
    float a=0.f;
    #pragma unroll
    for(int d=0;d<64;d++) a+=Wd[t*64+d]*s[d];
    cf[voff+t]=a;
  }
}

__global__ void k_loss2(const __half* __restrict__ P, const __half* __restrict__ Q,
                        float* __restrict__ cf, int N){
  __shared__ float sv1[64], sv2[64];
  __shared__ float sred[BS];
  int t=threadIdx.x;
  if(t<64){ sv1[t]=cf[C_V1+t]; sv2[t]=cf[C_V2+t]; }
  __syncthreads();
  int i=blockIdx.x*BS+t, st=gridDim.x*BS;
  float acc=0.f;
  for(int v=i; v<N; v+=st){
    const uint4* pr=(const uint4*)(P+(size_t)v*64);
    const uint4* qr=(const uint4*)(Q+(size_t)v*64);
    float a1=0.f,a2=0.f,b1=0.f,b2=0.f;
    #pragma unroll
    for(int c=0;c<8;c++){
      uint4 pu=pr[c], qu=qr[c];
      unsigned arr[4]={pu.x,pu.y,pu.z,pu.w};
      unsigned brr[4]={qu.x,qu.y,qu.z,qu.w};
      #pragma unroll
      for(int j=0;j<4;j++){
        int d=c*8+j*2;
        __half2 ph=*(const __half2*)&arr[j];
        __half2 qh=*(const __half2*)&brr[j];
        float2 pf=__half22float2(ph);
        float2 qf=__half22float2(qh);
        a1=fmaf(pf.x,sv1[d],a1); a1=fmaf(pf.y,sv1[d+1],a1);
        a2=fmaf(pf.x,sv2[d],a2); a2=fmaf(pf.y,sv2[d+1],a2);
        b1=fmaf(qf.x,sv1[d],b1); b1=fmaf(qf.y,sv1[d+1],b1);
        b2=fmaf(qf.x,sv2[d],b2); b2=fmaf(qf.y,sv2[d+1],b2);
      }
    }
    acc += softplusf(-a1)+softplusf(b1)+softplusf(-a2)+softplusf(b2);
  }
  sred[t]=acc;
  __syncthreads();
  for(int o=BS/2;o>0;o>>=1){ if(t<o) sred[t]+=sred[t+o]; __syncthreads(); }
  if(t==0) atomicAdd(&cf[C_LOSS], sred[0]);
}

__global__ void k_final(const float* __restrict__ cf, float* __restrict__ out, int N){
  if(blockIdx.x||threadIdx.x) return;
  out[0]=cf[C_LOSS]/(float)N;
}

extern "C" void kernel_launch(void* const* d_in, const int* in_sizes, int n_in,
                              void* d_out, int out_size, void* d_ws, size_t ws_size,
                              hipStream_t stream) {
  const float* feat    = (const float*)d_in[0];
  const float* Wenc    = (const float*)d_in[1];
  const float* Wdisc   = (const float*)d_in[2];
  const int*   src     = (const int*)d_in[3];
  const int*   dst     = (const int*)d_in[4];
  const int*   permneg = (const int*)d_in[5];
  const int*   perm1   = (const int*)d_in[6];
  const int*   perm2   = (const int*)d_in[7];
  float* out = (float*)d_out;

  int N = in_sizes[5];
  int E = in_sizes[3];
  int target = (int)((double)N*0.8);
  int NB = (N+BS-1)/BS;
  int WORDS = (N+31)/32;
  int NBK = (N+NR-1)/NR;           // radix buckets (256 nodes each)
  int gE = (E+BS-1)/BS; if(gE>4096) gE=4096;
  const int SUBB = 2048;
  const int R1B = 128, R1ROWS = SUBB/R1B;

  // workspace carve (256B-aligned chunks)
  char* w = (char*)d_ws;
  auto alloc = [&](size_t bytes)->void*{
    void* p = (void*)w;
    w += (bytes + 255) & ~(size_t)255;
    return p;
  };
  size_t szN = ((size_t)N*4 + 255) & ~(size_t)255;
  int*      ctrl    = (int*)     alloc(4096);
  int*      cntD    = (int*)     alloc(szN);
  int*      rowptrD = (int*)     alloc((size_t)(N+1)*4);
  int*      rhist   = (int*)     alloc((size_t)RB*NBK*4);
  int*      colD    = (int*)     alloc((size_t)E*4);
  unsigned long long* pairs = (unsigned long long*)alloc((size_t)E*8);
  int*      hop     = (int*)     alloc((size_t)N*4);
  int*      keepPk  = (int*)     alloc((size_t)N*4);
  unsigned* bits    = (unsigned*)alloc((size_t)WORDS*4);
  int*      wordpref= (int*)     alloc((size_t)(WORDS+1)*4);
  int*      part    = (int*)     alloc((size_t)(NB+2)*4);
  int*      hist    = (int*)     alloc(64*4);
  fp8*      FW      = (fp8*)     alloc((size_t)N*64);
  fp8*      FWn     = (fp8*)     alloc((size_t)N*64);
  __half*   P       = (__half*)  alloc((size_t)N*64*2);
  __half*   Q       = (__half*)  alloc((size_t)N*64*2);
  float*    sp1     = (float*)   alloc((size_t)SUBB*64*4);
  float*    sp2     = (float*)   alloc((size_t)SUBB*64*4);
  float*    sp1b    = (float*)   alloc((size_t)R1B*64*4);
  float*    sp2b    = (float*)   alloc((size_t)R1B*64*4);
  float*    cf = (float*)ctrl;

  // --- build in-CSR via radix partition (no global atomics in scatter) ---
  hipMemsetAsync(cntD, 0, szN, stream);
  k_deg1      <<<gE, BS, 0, stream>>>(dst, E, cntD);
  k_blocksum  <<<NB, BS, 0, stream>>>(cntD, N, part);
  k_scan_block<<<1,  BS, 0, stream>>>(part, NB);
  k_rowptr2   <<<NB, BS, 0, stream>>>(cntD, part, N, NB, rowptrD);
  k_rhist     <<<RB, BS, 0, stream>>>(dst, E, rhist, NBK);
  k_rscatter  <<<RB, BS, 0, stream>>>(src, dst, E, rhist, rowptrD, pairs, NBK, N);
  k_bplace    <<<NBK, BS, 0, stream>>>(rowptrD, pairs, colD, N);

  // --- FW = feat @ W_enc (fp8), FWn = FW[perm_neg] ---
  k_fw      <<<2048, BS, 0, stream>>>(feat, Wenc, FW, N);
  k_permrows<<<4096, BS, 0, stream>>>((const unsigned*)FW, permneg, (unsigned*)FWn, N);

  // --- per-perm: pull BFS + keep mask ---
  const int* perms[2] = {perm1, perm2};
  for(int pi=0; pi<2; pi++){
    const int* perm = perms[pi];
    k_bfs_init<<<NB, BS, 0, stream>>>(hop, N, perm, ctrl, hist, bits, WORDS, pi);
    for(int it=0; it<MAXIT; it++)
      k_pull<<<NB, BS, 0, stream>>>(rowptrD, colD, hop, perm, ctrl, it, N, target);
    k_histcut <<<NB, BS, 0, stream>>>(hop, N, hist, ctrl, target);
    k_flagscan<<<NB, BS, 0, stream>>>(hop, perm, bits, wordpref, N, WORDS, ctrl);
    k_keep    <<<NB, BS, 0, stream>>>(hop, perm, bits, wordpref, keepPk, N, ctrl, pi);
  }

  // --- fused gather: pos/neg rows + both subgraph summaries in one CSR pass ---
  k_mega     <<<SUBB, BS, 0, stream>>>(rowptrD, colD, (const unsigned char*)FW,
                                       (const unsigned char*)FWn, keepPk, P, Q, sp1, sp2, N);
  k_reduce_s1<<<R1B, BS, 0, stream>>>(sp1, sp2, SUBB, R1ROWS, sp1b, sp2b);
  k_reduce_s2<<<1,   BS, 0, stream>>>(sp1b, sp2b, R1B, cf);
  k_sumv     <<<1, 64, 0, stream>>>(Wdisc, cf, C_SUM1, C_V1, 1.f/(float)target);
  k_sumv     <<<1, 64, 0, stream>>>(Wdisc, cf, C_SUM2, C_V2, 1.f/(float)target);

  // --- streaming loss ---
  k_loss2<<<NB, BS, 0, stream>>>(P, Q, cf, N);
  k_final<<<1, 1, 0, stream>>>(cf, out, N);
}